// Round 8
// baseline (139.178 us; speedup 1.0000x reference)
//
#include <hip/hip_runtime.h>

// pred_vol (1,1,64,512,512) fp32; thresh 0.5; 9x9x9 max-pool NMS.
// Identity: thr is monotone and the window contains the center, so
// reference output == (c > 0.5 && c == max999_raw(x)) ? c : 0.
//
// v8 = v7 (TH=8 row-pair vertical sharing, triple-buffered DMA staging,
// dist-2 prefetch, counted vmcnt, single barrier/step, C-ring centers,
// 8-slot D-ring) with the bcol LDS round-trip replaced by DPP lane shifts:
//  - lanes are consecutive w4 columns, so col-max at w4+-1 lives in the
//    adjacent lane: v_mov_dpp wave_shr:1 / wave_shl:1 (VALU pipe, no LDS).
//  - only w4 63<->64 crosses the wave boundary; patched via a 512-B LDS
//    buffer written at vert(t), read at horiz(t) one step later -- published
//    by the existing top barrier, so still ONE barrier per step.
// LDS ops/thread/step: 16 -> ~10 (-30% incl. DMA writes); bcol (32 KB) freed.
static constexpr int Dd = 64;
static constexpr int Hh = 512;
static constexpr int Ww = 512;
static constexpr int RAD = 4;
static constexpr float THRESH_V = 0.5f;
static constexpr int W4 = Ww / 4;           // 128 float4 per row
static constexpr int PLANE4 = Hh * W4;      // 65536 float4 per D-plane

static constexpr int TH = 8;                // output h-rows per block
static constexpr int DC = 16;               // output d-planes per block
static constexpr int ROWS = TH + 2 * RAD;   // 16 staged raw rows per plane
static constexpr int NPL = DC + 2 * RAD;    // 24 planes; loop runs t=0..24
static constexpr int NBLK = (Hh / TH) * (Dd / DC);  // 256 blocks (1/CU)

typedef float nf4 __attribute__((ext_vector_type(4)));

__device__ __forceinline__ float4 f4max(float4 a, float4 b) {
    return make_float4(fmaxf(a.x, b.x), fmaxf(a.y, b.y), fmaxf(a.z, b.z), fmaxf(a.w, b.w));
}
__device__ __forceinline__ int iclamp(int v, int lo, int hi) {
    return v < lo ? lo : (v > hi ? hi : v);
}

// DPP lane shifts. Per LLVM's DPP-scan usage, *_SHR:1 => lane i reads lane
// i-1 (lane 0 invalid), *_SHL:1 => lane i reads lane i+1 (lane 63 invalid).
// bound_ctrl=false + old=src => invalid lanes keep their own value (clamp).
static constexpr int DPP_WAVE_SHR1 = 0x138;
static constexpr int DPP_WAVE_SHL1 = 0x130;
template <int CTRL>
__device__ __forceinline__ float4 f4dpp(float4 v) {
    float4 r;
    r.x = __int_as_float(__builtin_amdgcn_update_dpp(
        __float_as_int(v.x), __float_as_int(v.x), CTRL, 0xF, 0xF, false));
    r.y = __int_as_float(__builtin_amdgcn_update_dpp(
        __float_as_int(v.y), __float_as_int(v.y), CTRL, 0xF, 0xF, false));
    r.z = __int_as_float(__builtin_amdgcn_update_dpp(
        __float_as_int(v.z), __float_as_int(v.z), CTRL, 0xF, 0xF, false));
    r.w = __int_as_float(__builtin_amdgcn_update_dpp(
        __float_as_int(v.w), __float_as_int(v.w), CTRL, 0xF, 0xF, false));
    return r;
}

// Counted-vmcnt barrier: drains this wave's stage(t) DMA group while newer
// prefetch groups and output stores stay in flight. lgkmcnt(0) orders LDS.
#define BAR_VM(N) asm volatile("s_waitcnt vmcnt(" #N ") lgkmcnt(0)\n\ts_barrier" ::: "memory")
// LDS-only barrier (final step: publishes the last patch writes).
#define BAR_LDS() asm volatile("s_waitcnt lgkmcnt(0)\n\ts_barrier" ::: "memory")

// Direct global->LDS DMA, 16B per lane, dest = wave-uniform base + lane*16.
__device__ __forceinline__ void load_lds16(const float4* g, float4* l) {
    __builtin_amdgcn_global_load_lds(
        (const __attribute__((address_space(1))) void*)g,
        (__attribute__((address_space(3))) void*)l, 16, 0, 0);
}

// 96.5 KB LDS -> 1 block/CU; min-blocks=1 keeps the 256-VGPR cap.
__global__ __launch_bounds__(512, 1)
void fused_nms_k8(const float4* __restrict__ x4, float4* __restrict__ o4) {
    // 3 x 16-row raw buffers (96 KB) + wave-boundary patch buffer (512 B).
    __shared__ float4 braw[3][ROWS * W4];
    // bpatch[par][hs][0..1] = v0,v1 of col 63 (lm source for col 64)
    // bpatch[par][hs][2..3] = v0,v1 of col 64 (rm source for col 63)
    __shared__ float4 bpatch[2][4][4];

    const int tid  = threadIdx.x;
    const int w4   = tid & (W4 - 1);   // 0..127
    const int hs   = tid >> 7;         // 0..3 row-pair slot (owns rows 2hs,2hs+1)
    const int wid  = tid >> 6;         // wave 0..7
    const int lane = tid & 63;

    // XCD swizzle: band = blockIdx&7 -> h-band stays on one XCD's L2
    const int b    = blockIdx.x;
    const int band = b & 7;
    const int rest = b >> 3;           // 0..31
    const int ht   = band * 8 + (rest & 7);   // 0..63
    const int dc   = rest >> 3;        // 0..3
    const int h0   = ht * TH;
    const int d0   = dc * DC;

    // Staging: 32 segments (16 rows x 2 half-rows), 4 per wave.
    int goff[4], loff[4];
#pragma unroll
    for (int k = 0; k < 4; ++k) {
        const int s    = wid + 8 * k;          // 0..31
        const int row  = s >> 1;               // 0..15
        const int half = s & 1;                // 0/1
        const int gh   = iclamp(h0 - RAD + row, 0, Hh - 1);
        goff[k] = gh * W4 + half * 64 + lane;
        loff[k] = row * W4 + half * 64;
    }

    auto stage = [&](int p) {  // stage plane index p into braw[p % 3]
        const int gd = iclamp(d0 - RAD + p, 0, Dd - 1);
        const float4* pl = x4 + (size_t)gd * PLANE4;
        float4* dst = braw[p % 3];
#pragma unroll
        for (int k = 0; k < 4; ++k)
            load_lds16(pl + goff[k], dst + loff[k]);
    };

    // Horizontal 9-window: lm/rm are the neighbor-column col-maxes.
    auto hwin = [&](const float4 lm, const float4 cm, const float4 rm) -> float4 {
        const float l3 = lm.w, l2 = fmaxf(lm.z, l3), l1 = fmaxf(lm.y, l2), l0 = fmaxf(lm.x, l1);
        const float core = fmaxf(fmaxf(cm.x, cm.y), fmaxf(cm.z, cm.w));
        const float q0 = rm.x, q1 = fmaxf(q0, rm.y), q2 = fmaxf(q1, rm.z), q3 = fmaxf(q2, rm.w);
        float4 pm;
        pm.x = fmaxf(l0, fmaxf(core, q0));
        pm.y = fmaxf(l1, fmaxf(core, q1));
        pm.z = fmaxf(l2, fmaxf(core, q2));
        pm.w = fmaxf(l3, fmaxf(core, q3));
        return pm;
    };

    const bool needL = (w4 == 64);   // lane 0 of odd wave: lm from patch
    const bool needR = (w4 == 63);   // lane 63 of even wave: rm from patch

    // R: 8-slot ring of pm. At step t the ring holds pm(t-9..t-2); with this
    // step's pm(t-1) that's the 9-plane D-window for output plane t-9.
    // C: depth-5 center ring; read C[t%5] (plane t-5 == emitted plane's
    // index) before overwriting with plane t's center.
    float4 R0[8], R1[8];
    float4 C0[5], C1[5];
    float4 vp0, vp1;   // vert results of plane t-1 (own column)

    // Prologue: planes 0,1 staged; in-loop stage(t+2) covers 2..23.
    stage(0);
    stage(1);

    // 25 steps, fully unrolled: all parities/slots/vmcnt counts are static.
#pragma unroll
    for (int t = 0; t <= NPL; ++t) {
        const bool doV = (t <= NPL - 1);   // vertical for plane t (0..23)
        const bool doH = (t >= 1);         // horiz+ring for plane t-1
        const bool doE = (t >= 9);         // emit output plane d0 + t - 9

        // ONE barrier per step: publishes bpatch(t-1) writes AND drains
        // stage(t) (issued at step t-2; 4 DMA ops/wave). Per-wave VMEM ops
        // issued after stage(t): stores(t-2) x2 [t>=11], stage(t+1) x4
        // [t<=22], stores(t-1) x2 [t>=10].
        if (t <= 9)       { BAR_VM(4); }
        else if (t == 10) { BAR_VM(6); }
        else if (t <= 22) { BAR_VM(8); }
        else if (t == 23) { BAR_VM(4); }
        else              { BAR_LDS(); }

        // Distance-2 prefetch: ~2 full steps in flight.
        if (t + 2 <= NPL - 1) stage(t + 2);
        __builtin_amdgcn_sched_barrier(0);

        // ---- vertical for plane t: staged rows 2hs..2hs+9 (10 reads),
        //      shared 8-row core serving both owned windows.
        float4 nv0, nv1, nc0, nc1;
        if (doV) {
            const float4* Bc = &braw[t % 3][(2 * hs) * W4 + w4];
            float4 r0 = Bc[0 * W4], r1 = Bc[1 * W4], r2 = Bc[2 * W4], r3 = Bc[3 * W4];
            float4 r4 = Bc[4 * W4], r5 = Bc[5 * W4], r6 = Bc[6 * W4], r7 = Bc[7 * W4];
            float4 r8 = Bc[8 * W4], r9 = Bc[9 * W4];
            float4 core = f4max(f4max(f4max(r1, r2), f4max(r3, r4)),
                                f4max(f4max(r5, r6), f4max(r7, r8)));
            nv0 = f4max(core, r0);   // rows 2hs .. 2hs+8
            nv1 = f4max(core, r9);   // rows 2hs+1 .. 2hs+9
            // wave-boundary patch (published by next step's barrier)
            if (needR) { bpatch[t & 1][hs][0] = nv0; bpatch[t & 1][hs][1] = nv1; }
            if (needL) { bpatch[t & 1][hs][2] = nv0; bpatch[t & 1][hs][3] = nv1; }
            nc0 = r4;   // raw center, global row h0+2hs
            nc1 = r5;   // raw center, global row h0+2hs+1
        }

        // ---- horizontal + D-ring + emit for plane t-1: neighbor col-maxes
        //      via DPP lane shifts of vp0/vp1 (VALU), boundary via patch.
        if (doH) {
            const int p1 = (t - 1) & 1;
            float4 lm0 = f4dpp<DPP_WAVE_SHR1>(vp0);   // lane i <- i-1 (col-1)
            float4 lm1 = f4dpp<DPP_WAVE_SHR1>(vp1);
            float4 rm0 = f4dpp<DPP_WAVE_SHL1>(vp0);   // lane i <- i+1 (col+1)
            float4 rm1 = f4dpp<DPP_WAVE_SHL1>(vp1);
            if (needL) { lm0 = bpatch[p1][hs][0]; lm1 = bpatch[p1][hs][1]; }
            if (needR) { rm0 = bpatch[p1][hs][2]; rm1 = bpatch[p1][hs][3]; }
            const float4 pm0 = hwin(lm0, vp0, rm0);
            const float4 pm1 = hwin(lm1, vp1, rm1);

            if (doE) {
                const float4 cen0 = C0[t % 5];   // plane t-5 == emitted plane
                const float4 cen1 = C1[t % 5];
                float4 mm0 = pm0, mm1 = pm1;
#pragma unroll
                for (int i = 0; i < 8; ++i) { mm0 = f4max(mm0, R0[i]); mm1 = f4max(mm1, R1[i]); }
                const size_t obase = (size_t)(d0 + t - 9) * PLANE4
                                   + (size_t)(h0 + 2 * hs) * W4 + w4;
                nf4 q0, q1;
                q0.x = (cen0.x > THRESH_V && cen0.x == mm0.x) ? cen0.x : 0.0f;
                q0.y = (cen0.y > THRESH_V && cen0.y == mm0.y) ? cen0.y : 0.0f;
                q0.z = (cen0.z > THRESH_V && cen0.z == mm0.z) ? cen0.z : 0.0f;
                q0.w = (cen0.w > THRESH_V && cen0.w == mm0.w) ? cen0.w : 0.0f;
                q1.x = (cen1.x > THRESH_V && cen1.x == mm1.x) ? cen1.x : 0.0f;
                q1.y = (cen1.y > THRESH_V && cen1.y == mm1.y) ? cen1.y : 0.0f;
                q1.z = (cen1.z > THRESH_V && cen1.z == mm1.z) ? cen1.z : 0.0f;
                q1.w = (cen1.w > THRESH_V && cen1.w == mm1.w) ? cen1.w : 0.0f;
                __builtin_nontemporal_store(q0, (nf4*)&o4[obase]);
                __builtin_nontemporal_store(q1, (nf4*)&o4[obase + W4]);
            }
            R0[(t - 1) & 7] = pm0;   // overwrite after use
            R1[(t - 1) & 7] = pm1;
        }

        // ---- roll per-step registers (after all reads of the old values).
        if (doV) {
            vp0 = nv0;  vp1 = nv1;
            C0[t % 5] = nc0;  C1[t % 5] = nc1;   // slot read above first
        }
    }
}

extern "C" void kernel_launch(void* const* d_in, const int* in_sizes, int n_in,
                              void* d_out, int out_size, void* d_ws, size_t ws_size,
                              hipStream_t stream) {
    const float4* x4 = (const float4*)d_in[0];
    float4* out4 = (float4*)d_out;
    (void)d_ws; (void)ws_size; (void)in_sizes; (void)n_in; (void)out_size;
    fused_nms_k8<<<dim3(NBLK), dim3(512), 0, stream>>>(x4, out4);
}

// Round 9
// 124.862 us; speedup vs baseline: 1.1147x; 1.1147x over previous
//
#include <hip/hip_runtime.h>

// pred_vol (1,1,64,512,512) fp32; thresh 0.5; 9x9x9 max-pool NMS.
// Identity: thr is monotone and the window contains the center, so
// reference output == (c > 0.5 && c == max999_raw(x)) ? c : 0.
//
// v9 = v5's tile/occupancy (TH=4, 512 blocks, 2 blocks/CU, small rings)
//    + v7's single-barrier pipeline (vert(t) || horiz+emit(t-1))
//    + v8's DPP horizontal (verified correct; col-max at w4+-1 via
//      v_mov_dpp wave_shr/shl, wave-boundary 63<->64 via 256B LDS patch).
// Rationale: v5 is LDS-BW-bound (~94% of 128B/clk); v6/v7 cut bytes but
// fell to 1 block/CU (latency-bound); v8 spilled (VGPR 190 > 128 cap,
// WRITE_SIZE +28MB). v9 cuts the bcol round-trip (-20% LDS traffic) while
// keeping 2 blocks/CU and a ~110-VGPR footprint.
static constexpr int Dd = 64;
static constexpr int Hh = 512;
static constexpr int Ww = 512;
static constexpr int RAD = 4;
static constexpr float THRESH_V = 0.5f;
static constexpr int W4 = Ww / 4;           // 128 float4 per row
static constexpr int PLANE4 = Hh * W4;      // 65536 float4 per D-plane

static constexpr int TH = 4;                // output h-rows per block
static constexpr int DC = 16;               // output d-planes per block
static constexpr int ROWS = TH + 2 * RAD;   // 12 staged raw rows per plane
static constexpr int NPL = DC + 2 * RAD;    // 24 planes; loop runs t=0..24
static constexpr int NBLK = (Hh / TH) * (Dd / DC);  // 512 blocks (2/CU)

typedef float nf4 __attribute__((ext_vector_type(4)));

__device__ __forceinline__ float4 f4max(float4 a, float4 b) {
    return make_float4(fmaxf(a.x, b.x), fmaxf(a.y, b.y), fmaxf(a.z, b.z), fmaxf(a.w, b.w));
}
__device__ __forceinline__ int iclamp(int v, int lo, int hi) {
    return v < lo ? lo : (v > hi ? hi : v);
}

// DPP lane shifts (semantics verified by v8's absmax=0):
// WAVE_SHR1: lane i <- i-1 (lane 0 keeps own: correct left-edge clamp).
// WAVE_SHL1: lane i <- i+1 (lane 63 keeps own: correct right-edge clamp).
static constexpr int DPP_WAVE_SHR1 = 0x138;
static constexpr int DPP_WAVE_SHL1 = 0x130;
template <int CTRL>
__device__ __forceinline__ float4 f4dpp(float4 v) {
    float4 r;
    r.x = __int_as_float(__builtin_amdgcn_update_dpp(
        __float_as_int(v.x), __float_as_int(v.x), CTRL, 0xF, 0xF, false));
    r.y = __int_as_float(__builtin_amdgcn_update_dpp(
        __float_as_int(v.y), __float_as_int(v.y), CTRL, 0xF, 0xF, false));
    r.z = __int_as_float(__builtin_amdgcn_update_dpp(
        __float_as_int(v.z), __float_as_int(v.z), CTRL, 0xF, 0xF, false));
    r.w = __int_as_float(__builtin_amdgcn_update_dpp(
        __float_as_int(v.w), __float_as_int(v.w), CTRL, 0xF, 0xF, false));
    return r;
}

// Counted-vmcnt barrier: drains this wave's stage(t) DMA group while newer
// prefetch groups and output stores stay in flight. lgkmcnt(0) orders LDS.
#define BAR_VM(N) asm volatile("s_waitcnt vmcnt(" #N ") lgkmcnt(0)\n\ts_barrier" ::: "memory")
// LDS-only barrier (final step: publishes the last patch writes).
#define BAR_LDS() asm volatile("s_waitcnt lgkmcnt(0)\n\ts_barrier" ::: "memory")

// Direct global->LDS DMA, 16B per lane, dest = wave-uniform base + lane*16.
__device__ __forceinline__ void load_lds16(const float4* g, float4* l) {
    __builtin_amdgcn_global_load_lds(
        (const __attribute__((address_space(1))) void*)g,
        (__attribute__((address_space(3))) void*)l, 16, 0, 0);
}

// (512,2): 2 blocks/CU, 128-VGPR cap. 72.25 KB LDS fits 2 blocks (<80 KB).
__global__ __launch_bounds__(512, 2)
void fused_nms_k9(const float4* __restrict__ x4, float4* __restrict__ o4) {
    // 3 x 12-row raw buffers (72 KB) + wave-boundary patch (256 B).
    __shared__ float4 braw[3][ROWS * W4];
    // bpatch[par][hr][0] = v(col 63)  (lm source for col 64)
    // bpatch[par][hr][1] = v(col 64)  (rm source for col 63)
    __shared__ float4 bpatch[2][TH][2];

    const int tid  = threadIdx.x;
    const int w4   = tid & (W4 - 1);   // 0..127
    const int hr   = tid >> 7;         // 0..3 (output row within block)
    const int wid  = tid >> 6;         // wave 0..7
    const int lane = tid & 63;

    // XCD swizzle: band = blockIdx&7 -> h-band of 64 rows stays on one XCD's L2
    const int b    = blockIdx.x;
    const int band = b & 7;
    const int rest = b >> 3;           // 0..63
    const int ht   = band * 16 + (rest & 15);  // 0..127
    const int dc   = rest >> 4;        // 0..3
    const int h0   = ht * TH;
    const int d0   = dc * DC;
    const int outrow = (h0 + hr) * W4 + w4;

    // Staging descriptors: 24 segments (12 rows x 2 half-rows), 3 per wave.
    int goff[3], loff[3];
#pragma unroll
    for (int k = 0; k < 3; ++k) {
        const int s    = wid + 8 * k;          // 0..23
        const int row  = s >> 1;               // 0..11
        const int half = s & 1;                // 0/1
        const int gh   = iclamp(h0 - RAD + row, 0, Hh - 1);
        goff[k] = gh * W4 + half * 64 + lane;
        loff[k] = row * W4 + half * 64;
    }

    auto stage = [&](int p) {  // stage plane index p into braw[p % 3]
        const int gd = iclamp(d0 - RAD + p, 0, Dd - 1);
        const float4* pl = x4 + (size_t)gd * PLANE4;
        float4* dst = braw[p % 3];
#pragma unroll
        for (int k = 0; k < 3; ++k)
            load_lds16(pl + goff[k], dst + loff[k]);
    };

    // R: 8-slot ring of pm. At step t the ring holds pm(t-9..t-2); with this
    // step's pm(t-1) that's the 9-plane D-window for output plane d0+t-9
    // (window = plane indices t-9..t-1).
    // C: depth-5 center ring; emitted plane's index is t-5, whose center was
    // captured at step t-5 into C[t%5]; read before overwrite at step t.
    float4 R[8];
    float4 C[5];
    float4 vp;   // vert col-max of plane t-1 (own column)

    // Prologue: planes 0,1 staged; in-loop stage(t+2) covers 2..23.
    stage(0);
    stage(1);

    // 25 steps, fully unrolled: all parities/slots/vmcnt counts are static.
#pragma unroll
    for (int t = 0; t <= NPL; ++t) {
        const bool doV = (t <= NPL - 1);   // vertical for plane t (0..23)
        const bool doH = (t >= 1);         // horiz+ring for plane t-1
        const bool doE = (t >= 9);         // emit output plane d0 + t - 9

        // ONE barrier per step: publishes bpatch(t-1) AND drains stage(t)
        // (issued at step t-2; 3 DMA ops/wave). Per-wave VMEM ops issued
        // after stage(t): store(t-2) [t>=11], stage(t+1) x3 [t<=22],
        // store(t-1) [t>=10].
        if (t <= 9)       { BAR_VM(3); }
        else if (t == 10) { BAR_VM(4); }
        else if (t <= 22) { BAR_VM(5); }
        else if (t == 23) { BAR_VM(2); }
        else              { BAR_LDS(); }

        // Distance-2 prefetch: ~2 full steps in flight.
        if (t + 2 <= NPL - 1) stage(t + 2);
        __builtin_amdgcn_sched_barrier(0);

        // ---- vertical for plane t: 9 LDS reads at own column (rows
        //      hr..hr+8 of the 12-row span); r4 is the raw center.
        float4 nv, nc;
        if (doV) {
            const float4* Bc = &braw[t % 3][tid];   // hr*W4 + w4 == tid
            float4 r0 = Bc[0 * W4], r1 = Bc[1 * W4], r2 = Bc[2 * W4], r3 = Bc[3 * W4];
            float4 r4 = Bc[4 * W4];
            float4 r5 = Bc[5 * W4], r6 = Bc[6 * W4], r7 = Bc[7 * W4], r8 = Bc[8 * W4];
            nv = f4max(f4max(f4max(r0, r1), f4max(r2, r3)),
                       f4max(f4max(r4, r5), f4max(f4max(r6, r7), r8)));
            nc = r4;
            // wave-boundary patch (published by next step's barrier)
            if (w4 == 63) bpatch[t & 1][hr][0] = nv;
            if (w4 == 64) bpatch[t & 1][hr][1] = nv;
        }

        // ---- horizontal + D-ring + emit for plane t-1: neighbor col-maxes
        //      via DPP lane shifts of vp (VALU pipe); boundary via patch.
        if (doH) {
            const int p1 = (t - 1) & 1;
            float4 lm = f4dpp<DPP_WAVE_SHR1>(vp);   // col-1 (edges keep own)
            float4 rm = f4dpp<DPP_WAVE_SHL1>(vp);   // col+1 (edges keep own)
            if (w4 == 64) lm = bpatch[p1][hr][0];
            if (w4 == 63) rm = bpatch[p1][hr][1];
            const float l3 = lm.w, l2 = fmaxf(lm.z, l3), l1 = fmaxf(lm.y, l2), l0 = fmaxf(lm.x, l1);
            const float core = fmaxf(fmaxf(vp.x, vp.y), fmaxf(vp.z, vp.w));
            const float q0 = rm.x, q1 = fmaxf(q0, rm.y), q2 = fmaxf(q1, rm.z), q3 = fmaxf(q2, rm.w);
            float4 pm;
            pm.x = fmaxf(l0, fmaxf(core, q0));
            pm.y = fmaxf(l1, fmaxf(core, q1));
            pm.z = fmaxf(l2, fmaxf(core, q2));
            pm.w = fmaxf(l3, fmaxf(core, q3));

            if (doE) {
                const float4 cen = C[t % 5];   // plane t-5 == emitted plane
                float4 mm = pm;
#pragma unroll
                for (int i = 0; i < 8; ++i) mm = f4max(mm, R[i]);
                nf4 q;
                q.x = (cen.x > THRESH_V && cen.x == mm.x) ? cen.x : 0.0f;
                q.y = (cen.y > THRESH_V && cen.y == mm.y) ? cen.y : 0.0f;
                q.z = (cen.z > THRESH_V && cen.z == mm.z) ? cen.z : 0.0f;
                q.w = (cen.w > THRESH_V && cen.w == mm.w) ? cen.w : 0.0f;
                __builtin_nontemporal_store(
                    q, (nf4*)&o4[(size_t)(d0 + t - 9) * PLANE4 + outrow]);
            }
            R[(t - 1) & 7] = pm;   // overwrite after use
        }

        // ---- roll per-step registers (after all reads of the old values).
        if (doV) {
            vp = nv;
            C[t % 5] = nc;   // slot read above first
        }
    }
}

extern "C" void kernel_launch(void* const* d_in, const int* in_sizes, int n_in,
                              void* d_out, int out_size, void* d_ws, size_t ws_size,
                              hipStream_t stream) {
    const float4* x4 = (const float4*)d_in[0];
    float4* out4 = (float4*)d_out;
    (void)d_ws; (void)ws_size; (void)in_sizes; (void)n_in; (void)out_size;
    fused_nms_k9<<<dim3(NBLK), dim3(512), 0, stream>>>(x4, out4);
}

// Round 10
// 115.975 us; speedup vs baseline: 1.2001x; 1.0766x over previous
//
#include <hip/hip_runtime.h>

// pred_vol (1,1,64,512,512) fp32; thresh 0.5; 9x9x9 max-pool NMS.
// Identity: thr is monotone and the window contains the center, so
// reference output == (c > 0.5 && c == max999_raw(x)) ? c : 0.
//
// v10 = v6's halo economics at v5's wave count, proven components only:
//  - 1024-thread blocks (16 waves/CU, same TLP as v5's 2x8), ONE output
//    row per thread (v5/v9's exact per-thread structure, 88 VGPR measured).
//  - TH=8: 16 staged rows serve 8 output rows (halo amp 2x vs v5's 3x);
//    per-CU DMA segments/step 48 -> 32.
//  - triple-buffered braw (96 KB) + dist-2 prefetch + counted vmcnt.
//  - v7-style single barrier/step: vert(t) || horiz+emit(t-1), dbuf bcol.
//  - C-ring centers (no global re-load), 8-slot D-ring.
//  - NO DPP (v9 lesson: wave_shr/shl DPP is illegal on CDNA and lowers to
//    expensive cross-lane fallbacks -> 25% regression).
static constexpr int Dd = 64;
static constexpr int Hh = 512;
static constexpr int Ww = 512;
static constexpr int RAD = 4;
static constexpr float THRESH_V = 0.5f;
static constexpr int W4 = Ww / 4;           // 128 float4 per row
static constexpr int PLANE4 = Hh * W4;      // 65536 float4 per D-plane

static constexpr int TH = 8;                // output h-rows per block
static constexpr int DC = 16;               // output d-planes per block
static constexpr int ROWS = TH + 2 * RAD;   // 16 staged raw rows per plane
static constexpr int NPL = DC + 2 * RAD;    // 24 planes; loop runs t=0..24
static constexpr int NBLK = (Hh / TH) * (Dd / DC);  // 256 blocks (1/CU)

typedef float nf4 __attribute__((ext_vector_type(4)));

__device__ __forceinline__ float4 f4max(float4 a, float4 b) {
    return make_float4(fmaxf(a.x, b.x), fmaxf(a.y, b.y), fmaxf(a.z, b.z), fmaxf(a.w, b.w));
}
__device__ __forceinline__ int iclamp(int v, int lo, int hi) {
    return v < lo ? lo : (v > hi ? hi : v);
}

// Counted-vmcnt barrier: drains this wave's stage(t) DMA group while newer
// prefetch groups and output stores stay in flight. lgkmcnt(0) orders LDS.
#define BAR_VM(N) asm volatile("s_waitcnt vmcnt(" #N ") lgkmcnt(0)\n\ts_barrier" ::: "memory")
// LDS-only barrier (final step: publishes the last bcol writes).
#define BAR_LDS() asm volatile("s_waitcnt lgkmcnt(0)\n\ts_barrier" ::: "memory")

// Direct global->LDS DMA, 16B per lane, dest = wave-uniform base + lane*16.
__device__ __forceinline__ void load_lds16(const float4* g, float4* l) {
    __builtin_amdgcn_global_load_lds(
        (const __attribute__((address_space(1))) void*)g,
        (__attribute__((address_space(3))) void*)l, 16, 0, 0);
}

// 128 KB LDS -> 1 block/CU; 16 waves = 4 waves/SIMD -> 128-VGPR cap
// (structure measured at 88 VGPR in v9 -> no spill expected).
__global__ __launch_bounds__(1024, 1)
void fused_nms_k10(const float4* __restrict__ x4, float4* __restrict__ o4) {
    // 3 x 16-row raw buffers (96 KB) + 2 x 8-row col-max buffers (32 KB).
    __shared__ float4 braw[3][ROWS * W4];
    __shared__ float4 bcol[2][TH * W4];

    const int tid  = threadIdx.x;
    const int w4   = tid & (W4 - 1);   // 0..127
    const int hr   = tid >> 7;         // 0..7 (output row within block)
    const int wid  = tid >> 6;         // wave 0..15
    const int lane = tid & 63;

    // XCD swizzle: band = blockIdx&7 -> h-band of 64 rows stays on one XCD's L2
    const int b    = blockIdx.x;
    const int band = b & 7;
    const int rest = b >> 3;           // 0..31
    const int ht   = band * 8 + (rest & 7);   // 0..63
    const int dc   = rest >> 3;        // 0..3
    const int h0   = ht * TH;
    const int d0   = dc * DC;

    const int colm = w4 ? w4 - 1 : 0;
    const int colp = (w4 < W4 - 1) ? w4 + 1 : W4 - 1;
    const int outrow = (h0 + hr) * W4 + w4;

    // Staging: 32 segments (16 rows x 2 half-rows), 2 per wave.
    int goff[2], loff[2];
#pragma unroll
    for (int k = 0; k < 2; ++k) {
        const int s    = wid + 16 * k;         // 0..31
        const int row  = s >> 1;               // 0..15
        const int half = s & 1;                // 0/1
        const int gh   = iclamp(h0 - RAD + row, 0, Hh - 1);
        goff[k] = gh * W4 + half * 64 + lane;
        loff[k] = row * W4 + half * 64;
    }

    auto stage = [&](int p) {  // stage plane index p into braw[p % 3]
        const int gd = iclamp(d0 - RAD + p, 0, Dd - 1);
        const float4* pl = x4 + (size_t)gd * PLANE4;
        float4* dst = braw[p % 3];
        load_lds16(pl + goff[0], dst + loff[0]);
        load_lds16(pl + goff[1], dst + loff[1]);
    };

    // R: 8-slot ring of pm. At step t the ring holds pm(t-9..t-2); with this
    // step's pm(t-1) that's the 9-plane D-window for output plane d0+t-9
    // (window = plane indices t-9..t-1).
    // C: depth-5 center ring; emitted plane's index is t-5, whose center was
    // captured at step t-5 into C[t%5]; read before overwrite at step t.
    float4 R[8];
    float4 C[5];
    float4 vp;   // vert col-max of plane t-1 (own column)

    // Prologue: planes 0,1 staged; in-loop stage(t+2) covers 2..23.
    stage(0);
    stage(1);

    // 25 steps, fully unrolled: all parities/slots/vmcnt counts are static.
#pragma unroll
    for (int t = 0; t <= NPL; ++t) {
        const bool doV = (t <= NPL - 1);   // vertical for plane t (0..23)
        const bool doH = (t >= 1);         // horiz+ring for plane t-1
        const bool doE = (t >= 9);         // emit output plane d0 + t - 9

        // ONE barrier per step: publishes bcol(t-1) writes AND drains
        // stage(t) (issued at step t-2; 2 DMA ops/wave). Per-wave VMEM ops
        // issued after stage(t): store(t-2) [t>=11], stage(t+1) x2 [t<=22],
        // store(t-1) [t>=10].
        if (t <= 9)       { BAR_VM(2); }
        else if (t == 10) { BAR_VM(3); }
        else if (t <= 22) { BAR_VM(4); }
        else if (t == 23) { BAR_VM(2); }
        else              { BAR_LDS(); }

        // Distance-2 prefetch: ~2 full steps in flight.
        if (t + 2 <= NPL - 1) stage(t + 2);
        __builtin_amdgcn_sched_barrier(0);

        // ---- vertical for plane t: 9 LDS reads at own column (span rows
        //      hr..hr+8 of the 16-row span); r4 is the raw center (global
        //      row h0+hr, interior so clamp-exact).
        float4 nv, nc;
        if (doV) {
            const float4* Bc = &braw[t % 3][tid];   // tid == hr*W4 + w4
            float4 r0 = Bc[0 * W4], r1 = Bc[1 * W4], r2 = Bc[2 * W4], r3 = Bc[3 * W4];
            float4 r4 = Bc[4 * W4];
            float4 r5 = Bc[5 * W4], r6 = Bc[6 * W4], r7 = Bc[7 * W4], r8 = Bc[8 * W4];
            nv = f4max(f4max(f4max(r0, r1), f4max(r2, r3)),
                       f4max(f4max(r4, r5), f4max(f4max(r6, r7), r8)));
            nc = r4;
            bcol[t & 1][tid] = nv;   // published by NEXT step's barrier
        }

        // ---- horizontal + D-ring + emit for plane t-1 (bcol[(t-1)&1]
        //      published by this step's top barrier; own col-max in vp).
        if (doH) {
            const float4* Bp = &bcol[(t - 1) & 1][hr * W4];
            const float4 lm = Bp[colm];
            const float4 rm = Bp[colp];
            const float l3 = lm.w, l2 = fmaxf(lm.z, l3), l1 = fmaxf(lm.y, l2), l0 = fmaxf(lm.x, l1);
            const float core = fmaxf(fmaxf(vp.x, vp.y), fmaxf(vp.z, vp.w));
            const float q0 = rm.x, q1 = fmaxf(q0, rm.y), q2 = fmaxf(q1, rm.z), q3 = fmaxf(q2, rm.w);
            float4 pm;
            pm.x = fmaxf(l0, fmaxf(core, q0));
            pm.y = fmaxf(l1, fmaxf(core, q1));
            pm.z = fmaxf(l2, fmaxf(core, q2));
            pm.w = fmaxf(l3, fmaxf(core, q3));

            if (doE) {
                const float4 cen = C[t % 5];   // plane t-5 == emitted plane
                float4 mm = pm;
#pragma unroll
                for (int i = 0; i < 8; ++i) mm = f4max(mm, R[i]);
                nf4 q;
                q.x = (cen.x > THRESH_V && cen.x == mm.x) ? cen.x : 0.0f;
                q.y = (cen.y > THRESH_V && cen.y == mm.y) ? cen.y : 0.0f;
                q.z = (cen.z > THRESH_V && cen.z == mm.z) ? cen.z : 0.0f;
                q.w = (cen.w > THRESH_V && cen.w == mm.w) ? cen.w : 0.0f;
                __builtin_nontemporal_store(
                    q, (nf4*)&o4[(size_t)(d0 + t - 9) * PLANE4 + outrow]);
            }
            R[(t - 1) & 7] = pm;   // overwrite after use
        }

        // ---- roll per-step registers (after all reads of the old values).
        if (doV) {
            vp = nv;
            C[t % 5] = nc;   // slot read above first
        }
    }
}

extern "C" void kernel_launch(void* const* d_in, const int* in_sizes, int n_in,
                              void* d_out, int out_size, void* d_ws, size_t ws_size,
                              hipStream_t stream) {
    const float4* x4 = (const float4*)d_in[0];
    float4* out4 = (float4*)d_out;
    (void)d_ws; (void)ws_size; (void)in_sizes; (void)n_in; (void)out_size;
    fused_nms_k10<<<dim3(NBLK), dim3(1024), 0, stream>>>(x4, out4);
}